// Round 16
// baseline (75.041 us; speedup 1.0000x reference)
//
#include <hip/hip_runtime.h>

#define IMGW 28
#define OUTW 26
#define FLAT (OUTW * OUTW)
#define NCLS 10
#define WROW 28   // padded col stride in wL; class stride 112B, c0 16B-aligned

// TWO images per lane + row-halved blocks.
// Block = 512 thr = 8 waves; h = bid&1 selects output rows 0..12 / 13..25;
// g = bid>>1 selects a 128-image group: imgA = g*128+lane, imgB = imgA+64.
// Grid = 512 -> 2 blocks/CU -> 16 waves/CU = 4/SIMD (same residency as the
// 40.5us best), but each wave-uniform ds_read_b128 of weights now feeds
// 8 FMAs (2 images) instead of 4 -> DS-pipe work per image halved (~2.3x
// including the 13-row weight tile), and each ds/global latency window
// holds 2x independent VALU work. Register footprint kept ~95 (3-slot
// rolling 6-float buffers x 2 img = 36) so the (512,2) 128-VGPR cap is NOT
// hit -- R13/R14 both landed exactly at 128 and were allocator-strangled.
// Halves combine via 2-addend atomicAdd on memset-zeroed out (R15-proven,
// deterministic); bias added by h==0 only. Max loaded input row = s+14 = 27.
__global__ __launch_bounds__(512, 2) void fused_conv_fc_kernel(
    const float* __restrict__ x,       // [B, 784]
    const float* __restrict__ conv_w,  // [3,3]
    const float* __restrict__ fc_w,    // [10, 676]
    const float* __restrict__ fc_b,    // [10]
    float* __restrict__ out)           // [B, 10] (pre-zeroed)
{
    __shared__ float wL[13 * NCLS * WROW];      // 14560 B: this half's weights
    __shared__ float part[6][64][2][NCLS];      // 30720 B: waves1..6 partials

    const int tid  = threadIdx.x;
    const int lane = tid & 63;
    const int wid  = __builtin_amdgcn_readfirstlane(tid >> 6);
    const int h    = blockIdx.x & 1;
    const int imgA = (blockIdx.x >> 1) * 128 + lane;
    const int imgB = imgA + 64;
    const int s    = h * 13;                    // first output row of this half

    const float* ipA = x + (size_t)imgA * (IMGW * IMGW);
    const float* ipB = x + (size_t)imgB * (IMGW * IMGW);

    // stage this half's weights: wL[(rl*10+c)*28+cc] = fc_w[c*676+(s+rl)*26+cc]
    for (int i = tid; i < 13 * NCLS * WROW; i += 512) {
        int rl  = i / (NCLS * WROW);
        int rem = i - rl * (NCLS * WROW);
        int c   = rem / WROW;
        int cc  = rem - c * WROW;
        wL[i] = (cc < OUTW) ? fc_w[c * FLAT + (s + rl) * OUTW + cc] : 0.f;
    }

    const float cw0 = conv_w[0], cw1 = conv_w[1], cw2 = conv_w[2];
    const float cw3 = conv_w[3], cw4 = conv_w[4], cw5 = conv_w[5];
    const float cw6 = conv_w[6], cw7 = conv_w[7], cw8 = conv_w[8];

    __syncthreads();

    float aA[NCLS], aB[NCLS];
#pragma unroll
    for (int c = 0; c < NCLS; ++c) { aA[c] = 0.f; aB[c] = 0.f; }

    if (wid < 7) {
        const int  c0   = 4 * wid;                // 0,4,...,24 (16B-aligned)
        const int  wv   = (wid == 6) ? 2 : 4;     // valid out cols
        const bool full = (wid != 6);             // wave-uniform

        // 3-slot rolling row buffers, 6 floats, both images (36 VGPRs)
        __attribute__((aligned(16))) float A0[6], A1[6], A2[6];
        __attribute__((aligned(16))) float B0[6], B1[6], B2[6];

#define LOADR(BA, BB, RR) do {                                         \
        const float* _pa = ipA + (RR) * IMGW + c0;                     \
        const float* _pb = ipB + (RR) * IMGW + c0;                     \
        *(float4*)&BA[0] = *(const float4*)_pa;                        \
        *(float4*)&BB[0] = *(const float4*)_pb;                        \
        if (full) {                                                    \
            *(float2*)&BA[4] = *(const float2*)(_pa + 4);              \
            *(float2*)&BB[4] = *(const float2*)(_pb + 4);              \
        }                                                              \
    } while (0)

        if (!full) {   // slots 4,5 never written for wave6; keep finite
            A0[4]=A0[5]=A1[4]=A1[5]=A2[4]=A2[5]=0.f;
            B0[4]=B0[5]=B1[4]=B1[5]=B2[4]=B2[5]=0.f;
        }

        LOADR(A0, B0, s + 0); LOADR(A1, B1, s + 1); LOADR(A2, B2, s + 2);

        // body rl: conv h for both imgs; prefetch row s+rl+3 into slot L;
        // FC: 10 uniform b128 broadcasts, each feeding 8 FMAs.
#define BODY(P0, P1, P2, Q0, Q1, Q2, LA, LB, RL, RL_OK, RLOC) do {     \
        float hA[4], hB[4];                                            \
        _Pragma("unroll")                                              \
        for (int j = 0; j < 4; ++j) {                                  \
            float tA = P0[j]   * cw0 + P0[j+1] * cw1 + P0[j+2] * cw2   \
                     + P1[j]   * cw3 + P1[j+1] * cw4 + P1[j+2] * cw5   \
                     + P2[j]   * cw6 + P2[j+1] * cw7 + P2[j+2] * cw8;  \
            float tB = Q0[j]   * cw0 + Q0[j+1] * cw1 + Q0[j+2] * cw2   \
                     + Q1[j]   * cw3 + Q1[j+1] * cw4 + Q1[j+2] * cw5   \
                     + Q2[j]   * cw6 + Q2[j+1] * cw7 + Q2[j+2] * cw8;  \
            tA = fmaxf(tA, 0.f); tB = fmaxf(tB, 0.f);                  \
            hA[j] = (j >= wv) ? 0.f : tA;                              \
            hB[j] = (j >= wv) ? 0.f : tB;                              \
        }                                                              \
        if (RL_OK) LOADR(LA, LB, RL);                                  \
        const float* _w = &wL[(RLOC) * (NCLS * WROW) + c0];            \
        _Pragma("unroll")                                              \
        for (int c = 0; c < NCLS; ++c) {                               \
            float4 wf = *(const float4*)&_w[c * WROW];                 \
            aA[c] = fmaf(hA[0], wf.x, aA[c]);                          \
            aA[c] = fmaf(hA[1], wf.y, aA[c]);                          \
            aA[c] = fmaf(hA[2], wf.z, aA[c]);                          \
            aA[c] = fmaf(hA[3], wf.w, aA[c]);                          \
            aB[c] = fmaf(hB[0], wf.x, aB[c]);                          \
            aB[c] = fmaf(hB[1], wf.y, aB[c]);                          \
            aB[c] = fmaf(hB[2], wf.z, aB[c]);                          \
            aB[c] = fmaf(hB[3], wf.w, aB[c]);                          \
        }                                                              \
    } while (0)

        int rl = 0;
#pragma unroll 1
        for (int t4 = 0; t4 < 4; ++t4) {   // rl 0..11; loads reach s+14 <= 27
            BODY(A0, A1, A2, B0, B1, B2, A0, B0, s + rl + 3, true, rl + 0);
            BODY(A1, A2, A0, B1, B2, B0, A1, B1, s + rl + 4, true, rl + 1);
            BODY(A2, A0, A1, B2, B0, B1, A2, B2, s + rl + 5, true, rl + 2);
            rl += 3;
        }
        BODY(A0, A1, A2, B0, B1, B2, A0, B0, 0, false, 12);  // tail, no load
#undef LOADR
#undef BODY
    }

    if (wid >= 1 && wid < 7) {
#pragma unroll
        for (int c = 0; c < NCLS; ++c) {
            part[wid - 1][lane][0][c] = aA[c];
            part[wid - 1][lane][1][c] = aB[c];
        }
    }
    __syncthreads();
    if (wid == 0) {
        float* oA = out + (size_t)imgA * NCLS;
        float* oB = out + (size_t)imgB * NCLS;
#pragma unroll
        for (int c = 0; c < NCLS; ++c) {
            float tA = aA[c], tB = aB[c];
#pragma unroll
            for (int w = 0; w < 6; ++w) {
                tA += part[w][lane][0][c];
                tB += part[w][lane][1][c];
            }
            if (h == 0) { float bb = fc_b[c]; tA += bb; tB += bb; }
            atomicAdd(oA + c, tA);   // exactly 2 addends/loc -> deterministic
            atomicAdd(oB + c, tB);
        }
    }
}

extern "C" void kernel_launch(void* const* d_in, const int* in_sizes, int n_in,
                              void* d_out, int out_size, void* d_ws, size_t ws_size,
                              hipStream_t stream) {
    const float* x      = (const float*)d_in[0];
    const float* conv_w = (const float*)d_in[1];
    const float* fc_w   = (const float*)d_in[2];
    const float* fc_b   = (const float*)d_in[3];
    float* out = (float*)d_out;

    const int nimg   = in_sizes[0] / (IMGW * IMGW);  // 32768
    const int blocks = (nimg / 128) * 2;             // 512 half-blocks

    hipMemsetAsync(out, 0, (size_t)out_size * sizeof(float), stream);
    hipLaunchKernelGGL(fused_conv_fc_kernel, dim3(blocks), dim3(512), 0, stream,
                       x, conv_w, fc_w, fc_b, out);
}

// Round 18
// 37.079 us; speedup vs baseline: 2.0238x; 2.0238x over previous
//
#include <hip/hip_runtime.h>

#define IMGW 28
#define OUTW 26
#define FLAT (OUTW * OUTW)
#define NCLS 10
#define WROW 28              // weight col stride (floats)
#define XST  28              // xw per-image stride (floats)
#define SLOTSZ (64 * XST)    // 1792 floats per row-slot

// R7 compute structure (best: 40.5us) with ONE change: image rows reach
// lanes via a coalesced-staged rolling LDS window instead of per-lane
// scattered global loads (64 distinct cache lines per load instr = the
// theory for the universal ~40us latency wall; staging cuts line-walks ~4x).
// Pipeline per row X: g-issue @ body X-6 (1 f4/thread, ~500cy cover) ->
// ds_write @ X-4 -> ds_read to regs @ X-3 -> conv consumes @ X-2..X.
// Steady-state slot reuse: slot s read @ body X-3, rewritten @ body X
// (3 barriers apart). ROUND-17 BUG: the initial fill read slots 0..2
// right before body 0, so body 0's write of row 4 -> slot 0 raced with
// slower waves' read of row 0 (no barrier between). FIX: one extra
// __syncthreads() between initial fill and body 0.
// 7 col-strip waves compute (c0=4*wid; wave6 masks 2 cols, b128-only
// loads); all 8 waves stage. part[] reuses xw after the final barrier.
// LDS 57.8KB -> 2 blocks/CU.
__global__ __launch_bounds__(512, 2) void fused_conv_fc_kernel(
    const float* __restrict__ x,       // [B, 784]
    const float* __restrict__ conv_w,  // [3,3]
    const float* __restrict__ fc_w,    // [10, 676]
    const float* __restrict__ fc_b,    // [10]
    float* __restrict__ out)           // [B, 10]
{
    __shared__ float wL[OUTW * NCLS * WROW];  // 29120 B: wL[r][c][28]
    __shared__ float xw[4 * SLOTSZ];          // 28672 B; reused as part[] at end

    const int tid  = threadIdx.x;
    const int lane = tid & 63;
    const int wid  = __builtin_amdgcn_readfirstlane(tid >> 6);

    // ---- weight staging (as R7): wL[(r*10+c)*28+cc] = fc_w[c*676+r*26+cc]
    for (int i = tid; i < NCLS * FLAT; i += 512) {
        int c    = i / FLAT;
        int rest = i - c * FLAT;
        int r    = rest / OUTW;
        int cc   = rest - r * OUTW;
        wL[(r * NCLS + c) * WROW + cc] = fc_w[i];
    }
    for (int i = tid; i < OUTW * NCLS * 2; i += 512) {   // zero pad cols 26,27
        int rc = i >> 1;
        wL[rc * WROW + OUTW + (i & 1)] = 0.f;
    }

    const float cw0 = conv_w[0], cw1 = conv_w[1], cw2 = conv_w[2];
    const float cw3 = conv_w[3], cw4 = conv_w[4], cw5 = conv_w[5];
    const float cw6 = conv_w[6], cw7 = conv_w[7], cw8 = conv_w[8];

    // ---- staging lanes: thread t -> (img t/7, f4-chunk t%7), t<448
    const bool st   = (tid < 448);
    const int  simg = tid / 7;            // 0..63
    const int  sq   = tid - simg * 7;     // 0..6
    const float* gb = x + (size_t)(blockIdx.x * 64 + simg) * (IMGW * IMGW) + sq * 4;
    float*       lb = xw + simg * XST + sq * 4;

    float4 g4, g5, gA, gB;
    {   // prologue: issue rows 0..5, LDS-write rows 0..3
        float4 g0, g1, g2, g3;
        if (st) {
            g0 = *(const float4*)(gb + 0 * IMGW);
            g1 = *(const float4*)(gb + 1 * IMGW);
            g2 = *(const float4*)(gb + 2 * IMGW);
            g3 = *(const float4*)(gb + 3 * IMGW);
            g4 = *(const float4*)(gb + 4 * IMGW);
            g5 = *(const float4*)(gb + 5 * IMGW);
            *(float4*)(lb + 0 * SLOTSZ) = g0;
            *(float4*)(lb + 1 * SLOTSZ) = g1;
            *(float4*)(lb + 2 * SLOTSZ) = g2;
            *(float4*)(lb + 3 * SLOTSZ) = g3;
        }
    }
    __syncthreads();

    float acc[NCLS];
#pragma unroll
    for (int c = 0; c < NCLS; ++c) acc[c] = 0.f;

    const bool cmp  = (wid < 7);
    const int  c0   = cmp ? 4 * wid : 0;
    const int  wv   = (wid == 6) ? 2 : 4;
    const bool full = (wid != 6) && cmp;

    // rolling register rows: row X lives in bs[X%4]
    __attribute__((aligned(16))) float bs0[6], bs1[6], bs2[6], bs3[6];
    if (!full) { bs0[4]=bs0[5]=bs1[4]=bs1[5]=bs2[4]=bs2[5]=bs3[4]=bs3[5]=0.f; }

#define XRD(BN, SLOT) do {                                             \
    if (cmp) {                                                         \
        const float* _xs = &xw[(SLOT) * SLOTSZ + lane * XST + c0];     \
        *(float4*)&BN[0] = *(const float4*)_xs;                        \
        if (full) *(float2*)&BN[4] = *(const float2*)(_xs + 4);        \
    }                                                                  \
} while (0)

    // initial register fill: rows 0,1,2 (already in LDS)
    XRD(bs0, 0); XRD(bs1, 1); XRD(bs2, 2);
    __syncthreads();   // RACE FIX: initial slot-0 reads must complete before
                       // body 0 overwrites slot 0 with row 4

    // BODY r: [1] ds_read row r+3 -> BN (slot (r+3)%4, staged last body)
    //         [2] ds_write row r+4 from GW (g-issued 2 bodies ago)
    //         [3] g-issue row r+6 -> GI
    //         [4] conv h(r) from B0,B1,B2  [5] FC  [6] barrier
#define BODY(B0, B1, B2, BN, SLN, GW, GI, r, DO_RD, DO_WR, DO_IS) do { \
    if (DO_RD) XRD(BN, SLN);                                           \
    if (DO_WR && st) *(float4*)(lb + ((r) & 3) * SLOTSZ) = GW;         \
    if (DO_IS && st) GI = *(const float4*)(gb + ((r) + 6) * IMGW);     \
    if (cmp) {                                                         \
        float hh[4];                                                   \
        _Pragma("unroll")                                              \
        for (int j = 0; j < 4; ++j) {                                  \
            float t = B0[j]   * cw0 + B0[j+1] * cw1 + B0[j+2] * cw2    \
                    + B1[j]   * cw3 + B1[j+1] * cw4 + B1[j+2] * cw5    \
                    + B2[j]   * cw6 + B2[j+1] * cw7 + B2[j+2] * cw8;   \
            t = fmaxf(t, 0.f);                                         \
            hh[j] = (j >= wv) ? 0.f : t;                               \
        }                                                              \
        const float* _w = &wL[(r) * (NCLS * WROW) + c0];               \
        _Pragma("unroll")                                              \
        for (int c = 0; c < NCLS; ++c) {                               \
            float4 wf = *(const float4*)&_w[c * WROW];                 \
            acc[c] = fmaf(hh[0], wf.x, acc[c]);                        \
            acc[c] = fmaf(hh[1], wf.y, acc[c]);                        \
            acc[c] = fmaf(hh[2], wf.z, acc[c]);                        \
            acc[c] = fmaf(hh[3], wf.w, acc[c]);                        \
        }                                                              \
    }                                                                  \
    __syncthreads();                                                   \
} while (0)

    // bodies 0,1 (write prologue regs g4,g5 = rows 4,5)
    BODY(bs0, bs1, bs2, bs3, 3, g4, gA, 0, true, true, true);   // issue row 6
    BODY(bs1, bs2, bs3, bs0, 0, g5, gB, 1, true, true, true);   // issue row 7

    // bodies 2..21: 5 iterations x 4 phases (r = 2 mod 4 at phase 0)
    int r = 2;
#pragma unroll 1
    for (int t5 = 0; t5 < 5; ++t5) {
        BODY(bs2, bs3, bs0, bs1, 1, gA, gA, r + 0, true, true, true);
        BODY(bs3, bs0, bs1, bs2, 2, gB, gB, r + 1, true, true, true);
        BODY(bs0, bs1, bs2, bs3, 3, gA, gA, r + 2, true, true, true);
        BODY(bs1, bs2, bs3, bs0, 0, gB, gB, r + 3, true, true, true);
        r += 4;
    }

    // bodies 22..25: drain (no issue; writes stop after row 27)
    BODY(bs2, bs3, bs0, bs1, 1, gA, gA, 22, true,  true,  false); // write row 26
    BODY(bs3, bs0, bs1, bs2, 2, gB, gB, 23, true,  true,  false); // write row 27
    BODY(bs0, bs1, bs2, bs3, 3, gA, gA, 24, true,  false, false); // read row 27
    BODY(bs1, bs2, bs3, bs0, 0, gA, gA, 25, false, false, false);
#undef BODY
#undef XRD

    // ---- combine: reuse xw as part[6][64][10] (final body barrier protects)
    float* part = xw;
    if (wid >= 1 && wid < 7) {
#pragma unroll
        for (int c = 0; c < NCLS; ++c)
            part[((wid - 1) * 64 + lane) * NCLS + c] = acc[c];
    }
    __syncthreads();
    if (wid == 0) {
        float v[NCLS];
#pragma unroll
        for (int c = 0; c < NCLS; ++c) {
            float t = acc[c];
#pragma unroll
            for (int w = 0; w < 6; ++w) t += part[(w * 64 + lane) * NCLS + c];
            v[c] = t + fc_b[c];
        }
        float* o = out + (size_t)(blockIdx.x * 64 + lane) * NCLS;
#pragma unroll
        for (int q = 0; q < 5; ++q)
            *(float2*)(o + 2 * q) = make_float2(v[2 * q], v[2 * q + 1]);
    }
}

extern "C" void kernel_launch(void* const* d_in, const int* in_sizes, int n_in,
                              void* d_out, int out_size, void* d_ws, size_t ws_size,
                              hipStream_t stream) {
    const float* x      = (const float*)d_in[0];
    const float* conv_w = (const float*)d_in[1];
    const float* fc_w   = (const float*)d_in[2];
    const float* fc_b   = (const float*)d_in[3];
    float* out = (float*)d_out;

    const int nimg   = in_sizes[0] / (IMGW * IMGW);  // 32768
    const int blocks = nimg / 64;                    // 512 -> 2 blocks/CU

    hipLaunchKernelGGL(fused_conv_fc_kernel, dim3(blocks), dim3(512), 0, stream,
                       x, conv_w, fc_w, fc_b, out);
}

// Round 19
// 32.853 us; speedup vs baseline: 2.2842x; 1.1287x over previous
//
#include <hip/hip_runtime.h>

#define IMGW 28
#define OUTW 26
#define FLAT 676
#define NCLS 10
#define NFRAG 27            // 26 conv-row A-fragments + 1 bias fragment

typedef __bf16 bf16x8 __attribute__((ext_vector_type(8)));
typedef float  f32x4  __attribute__((ext_vector_type(4)));

// Pre-kernel: pack fc_w (+bias) into MFMA A-fragment order, bf16.
// Fragment r (<26) covers K-chunk = conv row r padded to 32 (cols 26..31 = 0).
// A-layout (16x16x32): lane l holds A[m=l&15][k=(l>>4)*8+j], j=0..7.
// Fragment 26 = bias at k==0 (multiplied by a ones-B later).
__global__ void pack_w_kernel(const float* __restrict__ fc_w,
                              const float* __restrict__ fc_b,
                              uint4* __restrict__ wfrag)
{
    int t = blockIdx.x * 256 + threadIdx.x;
    if (t >= NFRAG * 64) return;
    int r = t >> 6, l = t & 63;
    int cls = l & 15, kb = (l >> 4) * 8;
    unsigned short u[8];
#pragma unroll
    for (int j = 0; j < 8; ++j) {
        int k = kb + j;
        float v = 0.f;
        if (r < 26) { if (cls < NCLS && k < OUTW) v = fc_w[cls * FLAT + r * OUTW + k]; }
        else        { if (cls < NCLS && k == 0)   v = fc_b[cls]; }
        u[j] = __builtin_bit_cast(unsigned short, (__bf16)v);
    }
    uint4 o;
    o.x = (unsigned)u[0] | ((unsigned)u[1] << 16);
    o.y = (unsigned)u[2] | ((unsigned)u[3] << 16);
    o.z = (unsigned)u[4] | ((unsigned)u[5] << 16);
    o.w = (unsigned)u[6] | ((unsigned)u[7] << 16);
    wfrag[t] = o;
}

// Block = 512 thr = 8 waves, 64 images, grid 512 (2 blocks/CU).
// wave = (mt = wid&3: image tile of 16) x (kh = wid>>2: conv-row half
// 0..12 / 13..25). Lane l: img = mt*16 + (l&15), col-group cg = l>>4
// (cols 8cg..8cg+7). Per body (one conv row r): compute 8 h values from a
// 4-slot rolling 10-float register window (distance-2 global prefetch),
// relu, cvt to bf16 -> that IS the MFMA B-fragment (B[k][n]: n=l&15=img,
// k=(l>>4)*8+j=col). A-fragment: 1 ds_read_b128 from LDS. 1 MFMA
// accumulates D[class][img]. Cols 26..31 of h are garbage-but-finite;
// A holds zeros there so they cancel. No main-loop barriers. kh1 waves
// park D in LDS; kh0 adds, applies bias via fragment 26 x ones-B, stores.
// D-layout (m89-verified): col(n=img)=lane&15, row(class)=(lane>>4)*4+j.
__global__ __launch_bounds__(512, 2) void fused_conv_fc_kernel(
    const float* __restrict__ x,       // [B, 784]
    const float* __restrict__ conv_w,  // [3,3]
    const uint4* __restrict__ wfragG,  // [27*64] packed A-fragments
    float* __restrict__ out)           // [B, 10]
{
    __shared__ uint4 wfragL[NFRAG * 64];   // 27648 B
    __shared__ f32x4 dcomb[4][64];         // 4096 B

    const int tid  = threadIdx.x;
    const int lane = tid & 63;
    const int wid  = __builtin_amdgcn_readfirstlane(tid >> 6);

    for (int i = tid; i < NFRAG * 64; i += 512) wfragL[i] = wfragG[i];

    const float cw0 = conv_w[0], cw1 = conv_w[1], cw2 = conv_w[2];
    const float cw3 = conv_w[3], cw4 = conv_w[4], cw5 = conv_w[5];
    const float cw6 = conv_w[6], cw7 = conv_w[7], cw8 = conv_w[8];

    const int mt  = wid & 3;
    const int kh  = wid >> 2;
    const int s   = kh ? 13 : 0;               // first conv row of this half
    const int img = blockIdx.x * 64 + mt * 16 + (lane & 15);
    const int cg  = lane >> 4;                 // col group: cols 8cg..8cg+7
    const float* gb = x + (size_t)img * (IMGW * IMGW) + cg * 8;

    __syncthreads();

    // rolling input-row window: row s+i lives in slot i%4; 10 floats/slot
    // (taps for 8 h-cols need cols 8cg..8cg+9; cg==3 keeps only 4 real
    // floats, upper slots zeroed once -> h finite, zero-weighted anyway)
    float r0[10], r1[10], r2[10], r3[10];
    if (cg == 3) {
#pragma unroll
        for (int q = 4; q < 10; ++q) { r0[q]=0.f; r1[q]=0.f; r2[q]=0.f; r3[q]=0.f; }
    }

#define GLD(BUF, RR) do {                                              \
    const float* _p = gb + (RR) * IMGW;                                \
    *(float4*)&BUF[0] = *(const float4*)_p;                            \
    if (cg < 3) {                                                      \
        *(float4*)&BUF[4] = *(const float4*)(_p + 4);                  \
        *(float2*)&BUF[8] = *(const float2*)(_p + 8);                  \
    }                                                                  \
} while (0)

    f32x4 D = {0.f, 0.f, 0.f, 0.f};

#define BODY(A0, A1, A2, LD, RLD, FRI, DO_LD) do {                     \
    float hh[8];                                                       \
    _Pragma("unroll")                                                  \
    for (int j = 0; j < 8; ++j) {                                      \
        float t = A0[j]   * cw0 + A0[j+1] * cw1 + A0[j+2] * cw2        \
                + A1[j]   * cw3 + A1[j+1] * cw4 + A1[j+2] * cw5        \
                + A2[j]   * cw6 + A2[j+1] * cw7 + A2[j+2] * cw8;       \
        hh[j] = fmaxf(t, 0.f);                                         \
    }                                                                  \
    if (DO_LD) GLD(LD, RLD);                                           \
    bf16x8 bfr;                                                        \
    _Pragma("unroll")                                                  \
    for (int j = 0; j < 8; ++j) bfr[j] = (__bf16)hh[j];                \
    bf16x8 afr = __builtin_bit_cast(bf16x8, wfragL[(FRI) * 64 + lane]);\
    D = __builtin_amdgcn_mfma_f32_16x16x32_bf16(afr, bfr, D, 0, 0, 0); \
} while (0)

    GLD(r0, s + 0); GLD(r1, s + 1); GLD(r2, s + 2); GLD(r3, s + 3);

    int i = 0;
#pragma unroll 1
    for (int t2 = 0; t2 < 2; ++t2) {   // bodies 0..7; prefetch distance 2
        BODY(r0, r1, r2, r0, s + i + 4, s + i + 0, true);
        BODY(r1, r2, r3, r1, s + i + 5, s + i + 1, true);
        BODY(r2, r3, r0, r2, s + i + 6, s + i + 2, true);
        BODY(r3, r0, r1, r3, s + i + 7, s + i + 3, true);
        i += 4;
    }
    // bodies 8..12 (loads reach row s+14 <= 27; last body uses s+12..s+14)
    BODY(r0, r1, r2, r0, s + 12, s + 8,  true);
    BODY(r1, r2, r3, r1, s + 13, s + 9,  true);
    BODY(r2, r3, r0, r2, s + 14, s + 10, true);
    BODY(r3, r0, r1, r3, 0,      s + 11, false);
    BODY(r0, r1, r2, r0, 0,      s + 12, false);
#undef BODY
#undef GLD

    if (kh == 1) dcomb[mt][lane] = D;
    else {
        // bias: fragment 26 x ones-B (only k==0 lanes carry 1.0)
        bf16x8 ones;
#pragma unroll
        for (int j = 0; j < 8; ++j) ones[j] = (__bf16)0.f;
        if (lane < 16) ones[0] = (__bf16)1.0f;
        bf16x8 afr = __builtin_bit_cast(bf16x8, wfragL[26 * 64 + lane]);
        D = __builtin_amdgcn_mfma_f32_16x16x32_bf16(afr, ones, D, 0, 0, 0);
    }
    __syncthreads();
    if (kh == 0) {
        f32x4 Dp = dcomb[mt][lane];
        const int cbase = (lane >> 4) * 4;
        float* o = out + (size_t)img * NCLS;
#pragma unroll
        for (int j = 0; j < 4; ++j) {
            if (cbase + j < NCLS) o[cbase + j] = D[j] + Dp[j];
        }
    }
}

extern "C" void kernel_launch(void* const* d_in, const int* in_sizes, int n_in,
                              void* d_out, int out_size, void* d_ws, size_t ws_size,
                              hipStream_t stream) {
    const float* x      = (const float*)d_in[0];
    const float* conv_w = (const float*)d_in[1];
    const float* fc_w   = (const float*)d_in[2];
    const float* fc_b   = (const float*)d_in[3];
    float* out = (float*)d_out;
    uint4* wfrag = (uint4*)d_ws;   // needs 27*64*16 = 27648 B

    const int nimg   = in_sizes[0] / (IMGW * IMGW);  // 32768
    const int blocks = nimg / 64;                    // 512

    hipLaunchKernelGGL(pack_w_kernel,
                       dim3((NFRAG * 64 + 255) / 256), dim3(256), 0, stream,
                       fc_w, fc_b, wfrag);
    hipLaunchKernelGGL(fused_conv_fc_kernel, dim3(blocks), dim3(512), 0, stream,
                       x, conv_w, wfrag, out);
}